// Round 1
// baseline (247.160 us; speedup 1.0000x reference)
//
#include <hip/hip_runtime.h>

typedef float f32x4 __attribute__((ext_vector_type(4)));
typedef short s16x8 __attribute__((ext_vector_type(8)));
typedef short s16x4 __attribute__((ext_vector_type(4)));
typedef int   i32x4 __attribute__((ext_vector_type(4)));

using abfrag = s16x8;  // 8 bf16 = 4 VGPRs (guide §3 fragment type)

#define DI __device__ __forceinline__

DI unsigned short f2bf(float x) {  // RNE float->bf16
  unsigned u = __builtin_bit_cast(unsigned, x);
  u += 0x7fffu + ((u >> 16) & 1u);
  return (unsigned short)(u >> 16);
}
DI float bf2f(unsigned short h) {
  return __builtin_bit_cast(float, ((unsigned)h) << 16);
}

DI f32x4 MFMA(abfrag a, abfrag b, f32x4 c) {
  return __builtin_amdgcn_mfma_f32_16x16x32_bf16(a, b, c, 0, 0, 0);
}

// ---------------- fp32 -> bf16 conversion ----------------
__global__ void f2bf_kernel(const float* __restrict__ src,
                            unsigned short* __restrict__ dst, int n4) {
  int i = blockIdx.x * blockDim.x + threadIdx.x;
  const int stride = gridDim.x * blockDim.x;
  for (; i < n4; i += stride) {
    f32x4 v = ((const f32x4*)src)[i];
    s16x4 o;
#pragma unroll
    for (int j = 0; j < 4; ++j) o[j] = (short)f2bf(v[j]);
    ((s16x4*)dst)[i] = o;
  }
}

// ---------------- fused gml layer ----------------
// block = (n, pchunk of 128 cols). 4 waves; wave wv owns cols [32*wv, 32*wv+32)
// of the chunk, ALL 64 rows (4 m-frags x 2 n-frags).
// multi = h[n] (64xC) * W[g]^T (C x 128chunk)  -> registers
// xo    = G[n,g] (64x64) * multi (64x128chunk) -> B operand built in-register
// out   = max_g relu(xo) (+ residual)
template <int C, bool RES>
__global__ __launch_bounds__(256, 2) void gml_layer_kernel(
    const unsigned short* __restrict__ hin,   // [128][64][C] bf16
    const unsigned short* __restrict__ Wb,    // [4][512][C] bf16
    const float* __restrict__ bias,           // [4][512]
    const unsigned short* __restrict__ Gb,    // [128][4][64][64] bf16
    unsigned short* __restrict__ hout) {      // [128][64][512] bf16
  constexpr int KT = 64, LW = 72;  // 72*2B = 144B row stride (16B-aligned, padded)
  constexpr int NT = C / KT;
  __shared__ short sh_h[2][64][LW];
  __shared__ short sh_w[2][128][LW];
  __shared__ short sh_g[64][LW];

  const int tid = threadIdx.x;
  const int wv  = tid >> 6;
  const int l15 = tid & 15;
  const int gq  = (tid >> 4) & 3;
  const int bid = blockIdx.x;
  const int n   = bid & 127;
  const int pc0 = (bid >> 7) * 128;
  const int srow = tid >> 3;         // staging row 0..31
  const int scol = (tid & 7) * 8;    // staging col (elements)

  const unsigned short* hsrc = hin + (size_t)n * 64 * C;
  const unsigned short* gsrc = Gb + (size_t)n * 4 * 64 * 64;

  f32x4 xmax[4][2];
#pragma unroll
  for (int t = 0; t < 4; ++t)
#pragma unroll
    for (int u = 0; u < 2; ++u) xmax[t][u] = f32x4{0.f, 0.f, 0.f, 0.f};

  for (int g = 0; g < 4; ++g) {
    const unsigned short* wsrc = Wb + (size_t)(g * 512 + pc0) * C;
    f32x4 acc[4][2];
#pragma unroll
    for (int t = 0; t < 4; ++t)
#pragma unroll
      for (int u = 0; u < 2; ++u) acc[t][u] = f32x4{0.f, 0.f, 0.f, 0.f};

    // prologue global loads (tile 0 + G)
    i32x4 hr[2], wr[4], gr[2];
#pragma unroll
    for (int p = 0; p < 2; ++p)
      hr[p] = *(const i32x4*)(hsrc + (srow + p * 32) * C + scol);
#pragma unroll
    for (int p = 0; p < 4; ++p)
      wr[p] = *(const i32x4*)(wsrc + (srow + p * 32) * C + scol);
#pragma unroll
    for (int p = 0; p < 2; ++p)
      gr[p] = *(const i32x4*)(gsrc + g * 4096 + (srow + p * 32) * 64 + scol);

    __syncthreads();  // previous g's LDS reads (incl. xo's sh_g reads) done
#pragma unroll
    for (int p = 0; p < 2; ++p) *(i32x4*)&sh_h[0][srow + p * 32][scol] = hr[p];
#pragma unroll
    for (int p = 0; p < 4; ++p) *(i32x4*)&sh_w[0][srow + p * 32][scol] = wr[p];
#pragma unroll
    for (int p = 0; p < 2; ++p) *(i32x4*)&sh_g[srow + p * 32][scol] = gr[p];

    for (int kt = 0; kt < NT; ++kt) {
      const int cur = kt & 1;
      if (kt + 1 < NT) {  // prefetch next tile into regs
#pragma unroll
        for (int p = 0; p < 2; ++p)
          hr[p] = *(const i32x4*)(hsrc + (srow + p * 32) * C + (kt + 1) * KT + scol);
#pragma unroll
        for (int p = 0; p < 4; ++p)
          wr[p] = *(const i32x4*)(wsrc + (srow + p * 32) * C + (kt + 1) * KT + scol);
      }
      __syncthreads();  // staged tile `cur` visible; buffer 1-cur readers done
#pragma unroll
      for (int ks = 0; ks < 2; ++ks) {
        abfrag a[4], b[2];
#pragma unroll
        for (int t = 0; t < 4; ++t)
          a[t] = *(const abfrag*)&sh_h[cur][16 * t + l15][ks * 32 + gq * 8];
#pragma unroll
        for (int u = 0; u < 2; ++u)
          b[u] = *(const abfrag*)&sh_w[cur][32 * wv + 16 * u + l15][ks * 32 + gq * 8];
#pragma unroll
        for (int t = 0; t < 4; ++t)
#pragma unroll
          for (int u = 0; u < 2; ++u) acc[t][u] = MFMA(a[t], b[u], acc[t][u]);
      }
      if (kt + 1 < NT) {  // write prefetched regs to the other buffer
#pragma unroll
        for (int p = 0; p < 2; ++p) *(i32x4*)&sh_h[1 - cur][srow + p * 32][scol] = hr[p];
#pragma unroll
        for (int p = 0; p < 4; ++p) *(i32x4*)&sh_w[1 - cur][srow + p * 32][scol] = wr[p];
      }
    }

    // bias (added to multi, before xo)
    float bv[2];
#pragma unroll
    for (int u = 0; u < 2; ++u) bv[u] = bias[g * 512 + pc0 + 32 * wv + 16 * u + l15];
#pragma unroll
    for (int t = 0; t < 4; ++t)
#pragma unroll
      for (int u = 0; u < 2; ++u)
#pragma unroll
        for (int r = 0; r < 4; ++r) acc[t][u][r] += bv[u];

    // xo: B-frags from acc in-register. k-slot bijection (shared with A):
    // step s, lane-group gq, slot i -> j = 16s + 4gq + (i&3) + 32*(i>>2)
    // lane holds multi[16t + 4gq + r][..]: slots 0-3 <- acc[t=s], 4-7 <- acc[t=s+2]
    abfrag bb[2][2];
#pragma unroll
    for (int s = 0; s < 2; ++s)
#pragma unroll
      for (int u = 0; u < 2; ++u) {
        abfrag t8;
#pragma unroll
        for (int r = 0; r < 4; ++r) {
          t8[r]     = (short)f2bf(acc[s][u][r]);
          t8[4 + r] = (short)f2bf(acc[s + 2][u][r]);
        }
        bb[s][u] = t8;
      }
    f32x4 xg[4][2];
#pragma unroll
    for (int t = 0; t < 4; ++t)
#pragma unroll
      for (int u = 0; u < 2; ++u) xg[t][u] = f32x4{0.f, 0.f, 0.f, 0.f};
#pragma unroll
    for (int t = 0; t < 4; ++t) {
#pragma unroll
      for (int s = 0; s < 2; ++s) {
        // A = G rows 16t+l15, cols per same bijection: elements 16s+4gq(+32)
        const short* gp = &sh_g[16 * t + l15][16 * s + 4 * gq];
        s16x4 alo = *(const s16x4*)gp;
        s16x4 ahi = *(const s16x4*)(gp + 32);
        abfrag a;
#pragma unroll
        for (int j = 0; j < 4; ++j) { a[j] = alo[j]; a[4 + j] = ahi[j]; }
#pragma unroll
        for (int u = 0; u < 2; ++u) xg[t][u] = MFMA(a, bb[s][u], xg[t][u]);
      }
    }
#pragma unroll
    for (int t = 0; t < 4; ++t)
#pragma unroll
      for (int u = 0; u < 2; ++u)
#pragma unroll
        for (int r = 0; r < 4; ++r)
          xmax[t][u][r] = fmaxf(xmax[t][u][r], xg[t][u][r]);  // init 0 => relu
  }  // g

  // residual + store (D layout m89: col=lane&15, row=(lane>>4)*4+reg)
#pragma unroll
  for (int t = 0; t < 4; ++t)
#pragma unroll
    for (int u = 0; u < 2; ++u)
#pragma unroll
      for (int r = 0; r < 4; ++r) {
        const int m = 16 * t + 4 * gq + r;
        const int d = pc0 + 32 * wv + 16 * u + l15;
        float v = xmax[t][u][r];
        if constexpr (RES) v += bf2f(hin[(size_t)(n * 64 + m) * C + d]);
        hout[(size_t)(n * 64 + m) * 512 + d] = f2bf(v);
      }
}

// ---------------- final linear head ----------------
// per n: x1 = h[n] (64x512) * lin1_w^T (512x128) + b1; relu; x2 = x1 * w2 + b2
__global__ __launch_bounds__(256, 2) void final_kernel(
    const unsigned short* __restrict__ hin,  // [128][64][512] bf16
    const float* __restrict__ w1,            // [128][512]
    const float* __restrict__ b1,            // [128]
    const float* __restrict__ w2,            // [128]
    const float* __restrict__ b2,            // [1]
    float* __restrict__ out) {               // [128][64]
  constexpr int KT = 64, LW = 72, C = 512, NT = C / KT;
  __shared__ short sh_h[2][64][LW];
  __shared__ short sh_w[2][128][LW];
  __shared__ float red[4][64];
  const int tid = threadIdx.x;
  const int wv  = tid >> 6;
  const int l15 = tid & 15;
  const int gq  = (tid >> 4) & 3;
  const int n   = blockIdx.x;
  const int srow = tid >> 3;
  const int scol = (tid & 7) * 8;
  const unsigned short* hsrc = hin + (size_t)n * 64 * C;

  f32x4 acc[4][2];
#pragma unroll
  for (int t = 0; t < 4; ++t)
#pragma unroll
    for (int u = 0; u < 2; ++u) acc[t][u] = f32x4{0.f, 0.f, 0.f, 0.f};

  i32x4 hr[2], wr[4];
#pragma unroll
  for (int p = 0; p < 2; ++p)
    hr[p] = *(const i32x4*)(hsrc + (srow + p * 32) * C + scol);
#pragma unroll
  for (int p = 0; p < 4; ++p) {  // fp32 w1 -> bf16 in-stage
    const float* s = w1 + (srow + p * 32) * C + scol;
    f32x4 v0 = *(const f32x4*)s;
    f32x4 v1 = *(const f32x4*)(s + 4);
    s16x8 o;
#pragma unroll
    for (int j = 0; j < 4; ++j) { o[j] = (short)f2bf(v0[j]); o[4 + j] = (short)f2bf(v1[j]); }
    wr[p] = __builtin_bit_cast(i32x4, o);
  }
#pragma unroll
  for (int p = 0; p < 2; ++p) *(i32x4*)&sh_h[0][srow + p * 32][scol] = hr[p];
#pragma unroll
  for (int p = 0; p < 4; ++p) *(i32x4*)&sh_w[0][srow + p * 32][scol] = wr[p];

  for (int kt = 0; kt < NT; ++kt) {
    const int cur = kt & 1;
    if (kt + 1 < NT) {
#pragma unroll
      for (int p = 0; p < 2; ++p)
        hr[p] = *(const i32x4*)(hsrc + (srow + p * 32) * C + (kt + 1) * KT + scol);
#pragma unroll
      for (int p = 0; p < 4; ++p) {
        const float* s = w1 + (srow + p * 32) * C + (kt + 1) * KT + scol;
        f32x4 v0 = *(const f32x4*)s;
        f32x4 v1 = *(const f32x4*)(s + 4);
        s16x8 o;
#pragma unroll
        for (int j = 0; j < 4; ++j) { o[j] = (short)f2bf(v0[j]); o[4 + j] = (short)f2bf(v1[j]); }
        wr[p] = __builtin_bit_cast(i32x4, o);
      }
    }
    __syncthreads();
#pragma unroll
    for (int ks = 0; ks < 2; ++ks) {
      abfrag a[4], b[2];
#pragma unroll
      for (int t = 0; t < 4; ++t)
        a[t] = *(const abfrag*)&sh_h[cur][16 * t + l15][ks * 32 + gq * 8];
#pragma unroll
      for (int u = 0; u < 2; ++u)
        b[u] = *(const abfrag*)&sh_w[cur][32 * wv + 16 * u + l15][ks * 32 + gq * 8];
#pragma unroll
      for (int t = 0; t < 4; ++t)
#pragma unroll
        for (int u = 0; u < 2; ++u) acc[t][u] = MFMA(a[t], b[u], acc[t][u]);
    }
    if (kt + 1 < NT) {
#pragma unroll
      for (int p = 0; p < 2; ++p) *(i32x4*)&sh_h[1 - cur][srow + p * 32][scol] = hr[p];
#pragma unroll
      for (int p = 0; p < 4; ++p) *(i32x4*)&sh_w[1 - cur][srow + p * 32][scol] = wr[p];
    }
  }

  float b1v[2], w2v[2];
#pragma unroll
  for (int u = 0; u < 2; ++u) {
    b1v[u] = b1[32 * wv + 16 * u + l15];
    w2v[u] = w2[32 * wv + 16 * u + l15];
  }
  float part[4][4];
#pragma unroll
  for (int t = 0; t < 4; ++t)
#pragma unroll
    for (int r = 0; r < 4; ++r) {
      float s0 = 0.f;
#pragma unroll
      for (int u = 0; u < 2; ++u)
        s0 += fmaxf(acc[t][u][r] + b1v[u], 0.f) * w2v[u];
      part[t][r] = s0;
    }
  // reduce e-dim across the 16 lanes sharing the same rows
#pragma unroll
  for (int t = 0; t < 4; ++t)
#pragma unroll
    for (int r = 0; r < 4; ++r)
#pragma unroll
      for (int msk = 1; msk < 16; msk <<= 1)
        part[t][r] += __shfl_xor(part[t][r], msk);
  if (l15 == 0) {
#pragma unroll
    for (int t = 0; t < 4; ++t)
#pragma unroll
      for (int r = 0; r < 4; ++r) red[wv][16 * t + 4 * gq + r] = part[t][r];
  }
  __syncthreads();
  if (tid < 64)
    out[(size_t)n * 64 + tid] =
        red[0][tid] + red[1][tid] + red[2][tid] + red[3][tid] + b2[0];
}

// ---------------- host ----------------
extern "C" void kernel_launch(void* const* d_in, const int* in_sizes, int n_in,
                              void* d_out, int out_size, void* d_ws, size_t ws_size,
                              hipStream_t stream) {
  const float* G   = (const float*)d_in[0];
  const float* x   = (const float*)d_in[1];
  const float* W0  = (const float*)d_in[2];
  const float* b0  = (const float*)d_in[3];
  const float* W   = (const float*)d_in[4];
  const float* b   = (const float*)d_in[5];
  const float* l1w = (const float*)d_in[6];
  const float* l1b = (const float*)d_in[7];
  const float* l2w = (const float*)d_in[8];
  const float* l2b = (const float*)d_in[9];
  float* out = (float*)d_out;

  char* p = (char*)d_ws;
  unsigned short* W0b = (unsigned short*)p; p += (size_t)4 * 512 * 128 * 2;
  unsigned short* Wb  = (unsigned short*)p; p += (size_t)7 * 4 * 512 * 512 * 2;
  unsigned short* Gb  = (unsigned short*)p; p += (size_t)128 * 4 * 64 * 64 * 2;
  unsigned short* xb  = (unsigned short*)p; p += (size_t)128 * 64 * 128 * 2;
  unsigned short* hA  = (unsigned short*)p; p += (size_t)128 * 64 * 512 * 2;
  unsigned short* hB  = (unsigned short*)p; p += (size_t)128 * 64 * 512 * 2;
  // total ws use: 38,273,024 bytes

  auto cvt = [&](const float* s, unsigned short* d, long long nel) {
    int n4 = (int)(nel / 4);
    int blocks = (n4 + 255) / 256;
    if (blocks > 4096) blocks = 4096;
    f2bf_kernel<<<blocks, 256, 0, stream>>>(s, d, n4);
  };
  cvt(W0, W0b, 4LL * 512 * 128);
  cvt(W,  Wb,  7LL * 4 * 512 * 512);
  cvt(G,  Gb,  128LL * 4 * 64 * 64);
  cvt(x,  xb,  128LL * 64 * 128);

  gml_layer_kernel<128, false><<<512, 256, 0, stream>>>(xb, W0b, b0, Gb, hA);
  const unsigned short* src = hA;
  unsigned short* dst = hB;
  for (int i = 0; i < 7; ++i) {
    gml_layer_kernel<512, true><<<512, 256, 0, stream>>>(
        src, Wb + (size_t)i * 4 * 512 * 512, b + (size_t)i * 4 * 512, Gb, dst);
    const unsigned short* t = src; src = dst; dst = (unsigned short*)t;
  }
  // 7 swaps from (hA,hB): last output is hB == src
  final_kernel<<<128, 256, 0, stream>>>(src, l1w, l1b, l2w, l2b, out);
}

// Round 2
// 188.121 us; speedup vs baseline: 1.3138x; 1.3138x over previous
//
#include <hip/hip_runtime.h>

typedef float f32x4 __attribute__((ext_vector_type(4)));
typedef short s16x8 __attribute__((ext_vector_type(8)));
typedef short s16x4 __attribute__((ext_vector_type(4)));
typedef int   i32x4 __attribute__((ext_vector_type(4)));

using abfrag = s16x8;  // 8 bf16 = 4 VGPRs

#define DI __device__ __forceinline__

DI unsigned short f2bf(float x) {  // RNE float->bf16
  unsigned u = __builtin_bit_cast(unsigned, x);
  u += 0x7fffu + ((u >> 16) & 1u);
  return (unsigned short)(u >> 16);
}
DI float bf2f(unsigned short h) {
  return __builtin_bit_cast(float, ((unsigned)h) << 16);
}

DI f32x4 MFMA(abfrag a, abfrag b, f32x4 c) {
  return __builtin_amdgcn_mfma_f32_16x16x32_bf16(a, b, c, 0, 0, 0);
}

// async global->LDS DMA, 16B per lane. LDS dest = uniform base + lane*16
// (HW-fixed, m104); per-lane source address carries the swizzle (m173).
DI void gld16(void* lds_base, const void* gsrc) {
  __builtin_amdgcn_global_load_lds(
      (const __attribute__((address_space(1))) unsigned int*)gsrc,
      (__attribute__((address_space(3))) unsigned int*)lds_base, 16, 0, 0);
}

// ---------------- fp32 -> bf16 conversion ----------------
__global__ void f2bf_kernel(const float* __restrict__ src,
                            unsigned short* __restrict__ dst, int n4) {
  int i = blockIdx.x * blockDim.x + threadIdx.x;
  const int stride = gridDim.x * blockDim.x;
  for (; i < n4; i += stride) {
    f32x4 v = ((const f32x4*)src)[i];
    s16x4 o;
#pragma unroll
    for (int j = 0; j < 4; ++j) o[j] = (short)f2bf(v[j]);
    ((s16x4*)dst)[i] = o;
  }
}

// ---------------- fused gml layer (R2: loop-interchange + global_load_lds) ---
// block = (n, 128-col chunk). 4 waves; wave wv owns cols [32wv,32wv+32), all 64
// rows. K-loop outer over kt (KT=64), inner over all 4 groups with 4 live
// accumulators -> h A-frags read once per kt, reused 4x.
// LDS: lh [64][64] + lw [4][128][64], XOR slot-swizzle (slot ^= row&7),
// staged by global_load_lds with pre-swizzled per-lane source. G reuses lw.
template <int C, bool RES>
__global__ __launch_bounds__(256, 2) void gml_layer_kernel(
    const unsigned short* __restrict__ hin,   // [128][64][C] bf16
    const unsigned short* __restrict__ Wb,    // [4][512][C] bf16
    const float* __restrict__ bias,           // [4][512]
    const unsigned short* __restrict__ Gb,    // [128][4][64][64] bf16
    unsigned short* __restrict__ hout) {      // [128][64][512] bf16
  constexpr int NT = C / 64;
  __shared__ short lds[4096 + 4 * 128 * 64];  // 73728 B
  short* lh = lds;          // h tile  [64][64]
  short* lw = lds + 4096;   // W tiles [4][128][64]; G [4][64][64] reuses this

  const int tid  = threadIdx.x;
  const int wv   = tid >> 6;
  const int lane = tid & 63;
  const int l15  = tid & 15;
  const int l7   = l15 & 7;
  const int gq   = (tid >> 4) & 3;
  const int bid  = blockIdx.x;
  const int n    = bid & 127;
  const int pc0  = (bid >> 7) * 128;

  // per-lane DMA source pieces: dest row_local = 8j + (lane>>3), dest slot =
  // lane&7; source slot = dest_slot ^ (row&7) = (lane&7) ^ (lane>>3).
  const int lrow  = lane >> 3;
  const int lsoff = (((lane & 7) ^ lrow) << 3);  // element offset in row

  const unsigned short* hsrc = hin + (size_t)n * 64 * C;
  const unsigned short* wsrc = Wb + (size_t)(wv * 512 + pc0) * C;  // g = wv
  const unsigned short* gsrc = Gb + (size_t)(n * 4 + wv) * 4096;   // g = wv

  // bias preload; acc init = bias (bias added to multi before G-apply)
  float bvv[4][2];
#pragma unroll
  for (int g = 0; g < 4; ++g)
#pragma unroll
    for (int u = 0; u < 2; ++u)
      bvv[g][u] = bias[g * 512 + pc0 + 32 * wv + 16 * u + l15];

  f32x4 acc[4][4][2];
#pragma unroll
  for (int g = 0; g < 4; ++g)
#pragma unroll
    for (int t = 0; t < 4; ++t)
#pragma unroll
      for (int u = 0; u < 2; ++u)
        acc[g][t][u] = f32x4{bvv[g][u], bvv[g][u], bvv[g][u], bvv[g][u]};

  for (int kt = 0; kt < NT; ++kt) {
    // ---- stage h (2 instrs/wave) + W[g=wv] (16 instrs/wave) ----
    const unsigned short* hkt = hsrc + kt * 64 + lsoff;
#pragma unroll
    for (int j = 0; j < 2; ++j)
      gld16(lh + (16 * wv + 8 * j) * 64, hkt + (size_t)(16 * wv + 8 * j + lrow) * C);
    const unsigned short* wkt = wsrc + kt * 64 + lsoff;
#pragma unroll
    for (int j = 0; j < 16; ++j)
      gld16(lw + (wv * 128 + 8 * j) * 64, wkt + (size_t)(8 * j + lrow) * C);
    asm volatile("s_waitcnt vmcnt(0)" ::: "memory");
    __syncthreads();

    // ---- compute: A-frags once, reused across 4 groups ----
#pragma unroll
    for (int ks = 0; ks < 2; ++ks) {
      const int so = ((4 * ks + gq) ^ l7) << 3;  // swizzled element offset
      abfrag a[4];
#pragma unroll
      for (int t = 0; t < 4; ++t)
        a[t] = *(const abfrag*)&lh[(16 * t + l15) * 64 + so];
#pragma unroll
      for (int g = 0; g < 4; ++g) {
#pragma unroll
        for (int u = 0; u < 2; ++u) {
          abfrag b = *(const abfrag*)&lw[(g * 128 + 32 * wv + 16 * u + l15) * 64 + so];
#pragma unroll
          for (int t = 0; t < 4; ++t) acc[g][t][u] = MFMA(a[t], b, acc[g][t][u]);
        }
      }
    }
    __syncthreads();  // reads done -> next kt may overwrite
  }

  // ---- stage G[4][64][64] into lw region ----
#pragma unroll
  for (int j = 0; j < 8; ++j)
    gld16(lw + (wv * 64 + 8 * j) * 64, gsrc + (8 * j + lrow) * 64 + lsoff);
  asm volatile("s_waitcnt vmcnt(0)" ::: "memory");
  __syncthreads();

  // ---- xo = G * multi per group; relu+max fused ----
  f32x4 xmax[4][2];
#pragma unroll
  for (int t = 0; t < 4; ++t)
#pragma unroll
    for (int u = 0; u < 2; ++u) xmax[t][u] = f32x4{0.f, 0.f, 0.f, 0.f};

#pragma unroll
  for (int g = 0; g < 4; ++g) {
    // B-frags from acc[g] in-register. Shared k-slot bijection (verified R1):
    // step s, lane-group gq, slot i -> j = 16s + 4gq + (i&3) + 32*(i>>2)
    abfrag bb[2][2];
#pragma unroll
    for (int s = 0; s < 2; ++s)
#pragma unroll
      for (int u = 0; u < 2; ++u) {
        abfrag t8;
#pragma unroll
        for (int r = 0; r < 4; ++r) {
          t8[r]     = (short)f2bf(acc[g][s][u][r]);
          t8[4 + r] = (short)f2bf(acc[g][s + 2][u][r]);
        }
        bb[s][u] = t8;
      }
    f32x4 xg[4][2];
#pragma unroll
    for (int t = 0; t < 4; ++t)
#pragma unroll
      for (int u = 0; u < 2; ++u) xg[t][u] = f32x4{0.f, 0.f, 0.f, 0.f};
#pragma unroll
    for (int t = 0; t < 4; ++t) {
      const short* grow = lw + (g * 64 + 16 * t + l15) * 64;
#pragma unroll
      for (int s = 0; s < 2; ++s) {
        // A = G rows 16t+l15, elems 16s+4gq+{0..3} and +32, swizzled slots
        const int slot = 2 * s + (gq >> 1);
        const int e1 = ((slot ^ l7) << 3) + ((gq & 1) << 2);
        const int e2 = (((slot + 4) ^ l7) << 3) + ((gq & 1) << 2);
        s16x4 alo = *(const s16x4*)(grow + e1);
        s16x4 ahi = *(const s16x4*)(grow + e2);
        abfrag a;
#pragma unroll
        for (int j = 0; j < 4; ++j) { a[j] = alo[j]; a[4 + j] = ahi[j]; }
#pragma unroll
        for (int u = 0; u < 2; ++u) xg[t][u] = MFMA(a, bb[s][u], xg[t][u]);
      }
    }
#pragma unroll
    for (int t = 0; t < 4; ++t)
#pragma unroll
      for (int u = 0; u < 2; ++u)
#pragma unroll
        for (int r = 0; r < 4; ++r)
          xmax[t][u][r] = fmaxf(xmax[t][u][r], xg[t][u][r]);  // init 0 => relu
  }

  // ---- residual + store (C/D layout m89: col=lane&15, row=(lane>>4)*4+reg) --
#pragma unroll
  for (int t = 0; t < 4; ++t)
#pragma unroll
    for (int u = 0; u < 2; ++u)
#pragma unroll
      for (int r = 0; r < 4; ++r) {
        const int m = 16 * t + 4 * gq + r;
        const int d = pc0 + 32 * wv + 16 * u + l15;
        float v = xmax[t][u][r];
        if constexpr (RES) v += bf2f(hin[(size_t)(n * 64 + m) * C + d]);
        hout[(size_t)(n * 64 + m) * 512 + d] = f2bf(v);
      }
}

// ---------------- final linear head (unchanged from R1) ----------------
__global__ __launch_bounds__(256, 2) void final_kernel(
    const unsigned short* __restrict__ hin,  // [128][64][512] bf16
    const float* __restrict__ w1,            // [128][512]
    const float* __restrict__ b1,            // [128]
    const float* __restrict__ w2,            // [128]
    const float* __restrict__ b2,            // [1]
    float* __restrict__ out) {               // [128][64]
  constexpr int KT = 64, LW = 72, C = 512, NT = C / KT;
  __shared__ short sh_h[2][64][LW];
  __shared__ short sh_w[2][128][LW];
  __shared__ float red[4][64];
  const int tid = threadIdx.x;
  const int wv  = tid >> 6;
  const int l15 = tid & 15;
  const int gq  = (tid >> 4) & 3;
  const int n   = blockIdx.x;
  const int srow = tid >> 3;
  const int scol = (tid & 7) * 8;
  const unsigned short* hsrc = hin + (size_t)n * 64 * C;

  f32x4 acc[4][2];
#pragma unroll
  for (int t = 0; t < 4; ++t)
#pragma unroll
    for (int u = 0; u < 2; ++u) acc[t][u] = f32x4{0.f, 0.f, 0.f, 0.f};

  i32x4 hr[2], wr[4];
#pragma unroll
  for (int p = 0; p < 2; ++p)
    hr[p] = *(const i32x4*)(hsrc + (srow + p * 32) * C + scol);
#pragma unroll
  for (int p = 0; p < 4; ++p) {  // fp32 w1 -> bf16 in-stage
    const float* s = w1 + (srow + p * 32) * C + scol;
    f32x4 v0 = *(const f32x4*)s;
    f32x4 v1 = *(const f32x4*)(s + 4);
    s16x8 o;
#pragma unroll
    for (int j = 0; j < 4; ++j) { o[j] = (short)f2bf(v0[j]); o[4 + j] = (short)f2bf(v1[j]); }
    wr[p] = __builtin_bit_cast(i32x4, o);
  }
#pragma unroll
  for (int p = 0; p < 2; ++p) *(i32x4*)&sh_h[0][srow + p * 32][scol] = hr[p];
#pragma unroll
  for (int p = 0; p < 4; ++p) *(i32x4*)&sh_w[0][srow + p * 32][scol] = wr[p];

  for (int kt = 0; kt < NT; ++kt) {
    const int cur = kt & 1;
    if (kt + 1 < NT) {
#pragma unroll
      for (int p = 0; p < 2; ++p)
        hr[p] = *(const i32x4*)(hsrc + (srow + p * 32) * C + (kt + 1) * KT + scol);
#pragma unroll
      for (int p = 0; p < 4; ++p) {
        const float* s = w1 + (srow + p * 32) * C + (kt + 1) * KT + scol;
        f32x4 v0 = *(const f32x4*)s;
        f32x4 v1 = *(const f32x4*)(s + 4);
        s16x8 o;
#pragma unroll
        for (int j = 0; j < 4; ++j) { o[j] = (short)f2bf(v0[j]); o[4 + j] = (short)f2bf(v1[j]); }
        wr[p] = __builtin_bit_cast(i32x4, o);
      }
    }
    __syncthreads();
#pragma unroll
    for (int ks = 0; ks < 2; ++ks) {
      abfrag a[4], b[2];
#pragma unroll
      for (int t = 0; t < 4; ++t)
        a[t] = *(const abfrag*)&sh_h[cur][16 * t + l15][ks * 32 + gq * 8];
#pragma unroll
      for (int u = 0; u < 2; ++u)
        b[u] = *(const abfrag*)&sh_w[cur][32 * wv + 16 * u + l15][ks * 32 + gq * 8];
#pragma unroll
      for (int t = 0; t < 4; ++t)
#pragma unroll
        for (int u = 0; u < 2; ++u) acc[t][u] = MFMA(a[t], b[u], acc[t][u]);
    }
    if (kt + 1 < NT) {
#pragma unroll
      for (int p = 0; p < 2; ++p) *(i32x4*)&sh_h[1 - cur][srow + p * 32][scol] = hr[p];
#pragma unroll
      for (int p = 0; p < 4; ++p) *(i32x4*)&sh_w[1 - cur][srow + p * 32][scol] = wr[p];
    }
  }

  float b1v[2], w2v[2];
#pragma unroll
  for (int u = 0; u < 2; ++u) {
    b1v[u] = b1[32 * wv + 16 * u + l15];
    w2v[u] = w2[32 * wv + 16 * u + l15];
  }
  float part[4][4];
#pragma unroll
  for (int t = 0; t < 4; ++t)
#pragma unroll
    for (int r = 0; r < 4; ++r) {
      float s0 = 0.f;
#pragma unroll
      for (int u = 0; u < 2; ++u)
        s0 += fmaxf(acc[t][u][r] + b1v[u], 0.f) * w2v[u];
      part[t][r] = s0;
    }
#pragma unroll
  for (int t = 0; t < 4; ++t)
#pragma unroll
    for (int r = 0; r < 4; ++r)
#pragma unroll
      for (int msk = 1; msk < 16; msk <<= 1)
        part[t][r] += __shfl_xor(part[t][r], msk);
  if (l15 == 0) {
#pragma unroll
    for (int t = 0; t < 4; ++t)
#pragma unroll
      for (int r = 0; r < 4; ++r) red[wv][16 * t + 4 * gq + r] = part[t][r];
  }
  __syncthreads();
  if (tid < 64)
    out[(size_t)n * 64 + tid] =
        red[0][tid] + red[1][tid] + red[2][tid] + red[3][tid] + b2[0];
}

// ---------------- host ----------------
extern "C" void kernel_launch(void* const* d_in, const int* in_sizes, int n_in,
                              void* d_out, int out_size, void* d_ws, size_t ws_size,
                              hipStream_t stream) {
  const float* G   = (const float*)d_in[0];
  const float* x   = (const float*)d_in[1];
  const float* W0  = (const float*)d_in[2];
  const float* b0  = (const float*)d_in[3];
  const float* W   = (const float*)d_in[4];
  const float* b   = (const float*)d_in[5];
  const float* l1w = (const float*)d_in[6];
  const float* l1b = (const float*)d_in[7];
  const float* l2w = (const float*)d_in[8];
  const float* l2b = (const float*)d_in[9];
  float* out = (float*)d_out;

  char* p = (char*)d_ws;
  unsigned short* W0b = (unsigned short*)p; p += (size_t)4 * 512 * 128 * 2;
  unsigned short* Wb  = (unsigned short*)p; p += (size_t)7 * 4 * 512 * 512 * 2;
  unsigned short* Gb  = (unsigned short*)p; p += (size_t)128 * 4 * 64 * 64 * 2;
  unsigned short* xb  = (unsigned short*)p; p += (size_t)128 * 64 * 128 * 2;
  unsigned short* hA  = (unsigned short*)p; p += (size_t)128 * 64 * 512 * 2;
  unsigned short* hB  = (unsigned short*)p; p += (size_t)128 * 64 * 512 * 2;
  // total ws use: 38,273,024 bytes

  auto cvt = [&](const float* s, unsigned short* d, long long nel) {
    int n4 = (int)(nel / 4);
    int blocks = (n4 + 255) / 256;
    if (blocks > 4096) blocks = 4096;
    f2bf_kernel<<<blocks, 256, 0, stream>>>(s, d, n4);
  };
  cvt(W0, W0b, 4LL * 512 * 128);
  cvt(W,  Wb,  7LL * 4 * 512 * 512);
  cvt(G,  Gb,  128LL * 4 * 64 * 64);
  cvt(x,  xb,  128LL * 64 * 128);

  gml_layer_kernel<128, false><<<512, 256, 0, stream>>>(xb, W0b, b0, Gb, hA);
  const unsigned short* src = hA;
  unsigned short* dst = hB;
  for (int i = 0; i < 7; ++i) {
    gml_layer_kernel<512, true><<<512, 256, 0, stream>>>(
        src, Wb + (size_t)i * 4 * 512 * 512, b + (size_t)i * 4 * 512, Gb, dst);
    const unsigned short* t = src; src = dst; dst = (unsigned short*)t;
  }
  final_kernel<<<128, 256, 0, stream>>>(src, l1w, l1b, l2w, l2b, out);
}